// Round 2
// 128.115 us; speedup vs baseline: 1.2315x; 1.2315x over previous
//
#include <hip/hip_runtime.h>
#include <math.h>

#define NDET 4096
#define DIM  128
#define HID  64
#define NOSC 28
#define KPAD 64   // 28 cos + 28 sin, zero-padded to 64 for K%32==0

constexpr float TWO_PI_F = 6.28318530717958647692f;

typedef _Float16 f16x8 __attribute__((ext_vector_type(8)));
typedef float    f32x4 __attribute__((ext_vector_type(4)));

__device__ __forceinline__ unsigned f2sort(float f){
    unsigned u = __float_as_uint(f);
    return (u & 0x80000000u) ? ~u : (u | 0x80000000u);
}
__device__ __forceinline__ float sort2f(unsigned u){
    return __uint_as_float((u & 0x80000000u) ? (u & 0x7fffffffu) : ~u);
}
// broadcast lane t's value to all lanes (VALU pipe, no LDS)
__device__ __forceinline__ float lane_bcast(float v, int t){
    return __uint_as_float(__builtin_amdgcn_readlane(__float_as_uint(v), t));
}

// ---------------------------------------------------------------------------
// Encode: 2 rows per 64-lane wave, 4 waves/block, 1024 blocks.
// Outputs ROW-MAJOR split-fp16: for x = cos/sin value,
//   hi = fp16(x), lo = fp16(x - hi)   (|lo| <= 2^-12, its rounding <= 2^-23)
// Layout [row][k], k: 0..27 cos, 28..55 sin, 56..63 zero. sim is then
// reconstructed to ~1e-7 accuracy via 3 MFMA chains (hi*hi + hi*lo + lo*hi),
// which keeps the greedy-match argmax bit-stable vs the fp32 reference.
// ---------------------------------------------------------------------------
__global__ __launch_bounds__(256) void encode_kernel(
    const float* __restrict__ det_t, const float* __restrict__ det_t1,
    const float* __restrict__ Wp1, const float* __restrict__ bp1,
    const float* __restrict__ Wp2, const float* __restrict__ bp2,
    const float* __restrict__ Wa1, const float* __restrict__ ba1,
    const float* __restrict__ Wa2, const float* __restrict__ ba2,
    _Float16* __restrict__ Ahi, _Float16* __restrict__ Alo,
    _Float16* __restrict__ Bhi, _Float16* __restrict__ Blo)
{
    const int tid  = threadIdx.x;
    const int lane = tid & 63;
    const int wv   = tid >> 6;
    const int b    = blockIdx.x;
    const bool isT = b < 512;
    const int lr = __builtin_amdgcn_readfirstlane(((b & 511) << 3) + wv * 2);
    const float* __restrict__ src = (isT ? det_t : det_t1) + (size_t)lr * DIM;

    // ---- layer 1: phase (+amp for t rows), fused over d ----
    float h0 = bp1[lane], h1 = h0;
    float g0 = 0.0f, g1 = 0.0f;
    if (isT){
        g0 = ba1[lane]; g1 = g0;
        #pragma unroll 8
        for (int d = 0; d < DIM; ++d){
            float x0 = src[d], x1 = src[DIM + d];   // wave-uniform -> s_load
            float wp = Wp1[d * HID + lane];
            float wa = Wa1[d * HID + lane];
            h0 = fmaf(x0, wp, h0);  h1 = fmaf(x1, wp, h1);
            g0 = fmaf(x0, wa, g0);  g1 = fmaf(x1, wa, g1);
        }
        g0 = fmaxf(g0, 0.0f); g1 = fmaxf(g1, 0.0f);
    } else {
        #pragma unroll 8
        for (int d = 0; d < DIM; ++d){
            float x0 = src[d], x1 = src[DIM + d];
            float wp = Wp1[d * HID + lane];
            h0 = fmaf(x0, wp, h0);  h1 = fmaf(x1, wp, h1);
        }
    }
    h0 = fmaxf(h0, 0.0f); h1 = fmaxf(h1, 0.0f);

    // ---- layer 2: oscillator k = lane&31 (valid < 28); both rows parallel ----
    const int k  = lane & 31;
    const bool kv = k < NOSC;
    const int kc = kv ? k : 0;

    float pa = bp2[kc], pb = pa;
    #pragma unroll 16
    for (int t = 0; t < HID; ++t){
        float w2 = Wp2[t * NOSC + kc];          // 7KB, L1-hot
        pa = fmaf(lane_bcast(h0, t), w2, pa);
        pb = fmaf(lane_bcast(h1, t), w2, pb);
    }
    float aa = 0.0f, ab = 0.0f;
    if (isT){
        aa = ba2[kc]; ab = aa;
        #pragma unroll 16
        for (int t = 0; t < HID; ++t){
            float w2 = Wa2[t * NOSC + kc];
            aa = fmaf(lane_bcast(g0, t), w2, aa);
            ab = fmaf(lane_bcast(g1, t), w2, ab);
        }
    }

    const bool hiHalf = lane >= 32;
    float p2 = hiHalf ? pb : pa;
    float ph = fmodf(p2, TWO_PI_F);
    if (ph < 0.0f) ph += TWO_PI_F;               // python-style mod, [0, 2pi)

    // ---- Kuramoto evolve (t rows only); butterfly within each 32-lane half ----
    if (isT){
        float a2 = hiHalf ? ab : aa;
        float am = fmaxf(a2, 0.0f) + log1pf(expf(-fabsf(a2)));   // stable softplus
        const float omega = TWO_PI_F * ((k < 4) ? 2.0f : (k < 12) ? 6.0f : 40.0f);
        for (int s5 = 0; s5 < 5; ++s5){
            float sn, cs;
            sincosf(ph, &sn, &cs);
            float c = kv ? cs : 0.0f;
            float s = kv ? sn : 0.0f;
            float sc = c, ss = s;
            sc += __shfl_xor(sc, 16); ss += __shfl_xor(ss, 16);
            sc += __shfl_xor(sc,  8); ss += __shfl_xor(ss,  8);
            sc += __shfl_xor(sc,  4); ss += __shfl_xor(ss,  4);
            sc += __shfl_xor(sc,  2); ss += __shfl_xor(ss,  2);
            sc += __shfl_xor(sc,  1); ss += __shfl_xor(ss,  1);
            float mc = sc * (1.0f / NOSC);
            float ms = ss * (1.0f / NOSC);
            float coupling = ms * c - mc * s;
            ph += 0.01f * (omega + am * coupling);
            ph = fmodf(ph, TWO_PI_F);
            if (ph < 0.0f) ph += TWO_PI_F;
        }
    }

    const int row = lr + (hiHalf ? 1 : 0);
    _Float16* __restrict__ dhi = isT ? Ahi : Bhi;
    _Float16* __restrict__ dlo = isT ? Alo : Blo;
    const size_t rb = (size_t)row * KPAD;
    if (kv){
        float sn, cs;
        sincosf(ph, &sn, &cs);
        _Float16 ch = (_Float16)cs;
        _Float16 sh = (_Float16)sn;
        _Float16 cl = (_Float16)(cs - (float)ch);
        _Float16 sl = (_Float16)(sn - (float)sh);
        dhi[rb + k]        = ch;
        dhi[rb + NOSC + k] = sh;
        dlo[rb + k]        = cl;
        dlo[rb + NOSC + k] = sl;
    } else {
        // lanes k=28..31 zero-fill the K padding, positions 56..63
        const int kk = k - NOSC;
        dhi[rb + 56 + kk] = (_Float16)0.0f;
        dhi[rb + 60 + kk] = (_Float16)0.0f;
        dlo[rb + 56 + kk] = (_Float16)0.0f;
        dlo[rb + 60 + kk] = (_Float16)0.0f;
    }
}

// ---------------------------------------------------------------------------
// Sim via split-fp16 MFMA: sim = Ahi*Bhi + Ahi*Blo + Alo*Bhi (error ~1e-7).
// Swapped operands: mfma(B_frag, A_frag) so each lane's register quad holds
// 4 CONSECUTIVE columns j -> float4 stores + 2-step shuffle argmax.
// 64x64 tile per wave, 2x2 waves per block (128x128), grid 32x32.
// Operands (2 MB, fp16) are L2-resident -> loaded directly from global,
// no LDS, no barriers. v_mfma_f32_16x16x32_f16 layouts:
//   A-slot: lane holds A[l&15][(l>>4)*8 + 0..7]    (one contiguous 16B read)
//   D:      lane holds D[(l>>4)*4 + r][l&15]
// jb loop kept ROLLED (unroll 1) so live fragments stay ~130 VGPR (no spill);
// all register arrays inside are statically indexed (rule #20).
// Kernel is write-bound: 64 MiB sim output.
// ---------------------------------------------------------------------------
__global__ __launch_bounds__(256) void sim_kernel(
    const _Float16* __restrict__ Ahi, const _Float16* __restrict__ Alo,
    const _Float16* __restrict__ Bhi, const _Float16* __restrict__ Blo,
    float* __restrict__ sim_out, unsigned long long* __restrict__ rowmax)
{
    const int tid  = threadIdx.x;
    const int lane = tid & 63;
    const int wid  = tid >> 6;
    const int i0 = blockIdx.y * 128 + (wid & 1) * 64;
    const int j0 = blockIdx.x * 128 + (wid >> 1) * 64;
    const int r16 = lane & 15;
    const int g   = lane >> 4;          // k-group on input, j-quad on output

    // A-row fragments (B-slot of mfma): 16 x 16B per lane, L2 hits
    f16x8 ahi[4][2], alo[4][2];
    #pragma unroll
    for (int ib = 0; ib < 4; ++ib)
        #pragma unroll
        for (int kc = 0; kc < 2; ++kc){
            const size_t off = (size_t)(i0 + ib*16 + r16) * KPAD + kc*32 + g*8;
            ahi[ib][kc] = *(const f16x8*)&Ahi[off];
            alo[ib][kc] = *(const f16x8*)&Alo[off];
        }

    const float inv_denom =
        (float)(1.0 / ((5.2915026221291814 + 1e-6) * (5.2915026221291814 + 1e-6)));

    float bv[4] = {-3.4e38f, -3.4e38f, -3.4e38f, -3.4e38f};
    int   bj[4] = {0, 0, 0, 0};

    #pragma unroll 1
    for (int jb = 0; jb < 4; ++jb){
        f16x8 bhi[2], blo[2];
        #pragma unroll
        for (int kc = 0; kc < 2; ++kc){
            const size_t off = (size_t)(j0 + jb*16 + r16) * KPAD + kc*32 + g*8;
            bhi[kc] = *(const f16x8*)&Bhi[off];
            blo[kc] = *(const f16x8*)&Blo[off];
        }

        f32x4 acc[4] = {};   // [ib]
        #pragma unroll
        for (int ib = 0; ib < 4; ++ib){
            #pragma unroll
            for (int kc = 0; kc < 2; ++kc){
                acc[ib] = __builtin_amdgcn_mfma_f32_16x16x32_f16(bhi[kc], alo[ib][kc], acc[ib], 0, 0, 0);
                acc[ib] = __builtin_amdgcn_mfma_f32_16x16x32_f16(blo[kc], ahi[ib][kc], acc[ib], 0, 0, 0);
                acc[ib] = __builtin_amdgcn_mfma_f32_16x16x32_f16(bhi[kc], ahi[ib][kc], acc[ib], 0, 0, 0);
            }
        }

        // lane l holds sim[i0+ib*16+r16][j0+jb*16+g*4 + r], r=0..3
        #pragma unroll
        for (int ib = 0; ib < 4; ++ib){
            const int i = i0 + ib*16 + r16;
            f32x4 v = acc[ib];
            float4 out = make_float4(v[0]*inv_denom, v[1]*inv_denom,
                                     v[2]*inv_denom, v[3]*inv_denom);
            *(float4*)&sim_out[(size_t)i * NDET + j0 + jb*16 + g*4] = out;
            float vv[4] = {out.x, out.y, out.z, out.w};
            #pragma unroll
            for (int r = 0; r < 4; ++r){             // ascending j: first-wins ties
                if (vv[r] > bv[ib]){ bv[ib] = vv[r]; bj[ib] = j0 + jb*16 + g*4 + r; }
            }
        }
    }

    #pragma unroll
    for (int ib = 0; ib < 4; ++ib){
        const int i = i0 + ib*16 + r16;
        unsigned long long key =
            ((unsigned long long)f2sort(bv[ib]) << 32) | (unsigned)(NDET - 1 - bj[ib]);
        unsigned long long o;
        o = __shfl_xor(key, 16); if (o > key) key = o;
        o = __shfl_xor(key, 32); if (o > key) key = o;
        if (g == 0) atomicMax(&rowmax[i], key);
    }
}

// ---------------------------------------------------------------------------
// Greedy match, claim+finalize fused: single block, colwin lives in LDS.
// Winner of column j = claimant with max (max_sim, -row) — the scan-order
// semantics of the reference.
// ---------------------------------------------------------------------------
__global__ __launch_bounds__(1024) void match_kernel(
    const unsigned long long* __restrict__ rowmax,
    float* __restrict__ matches)
{
    __shared__ unsigned long long colwin[NDET];      // 32 KiB
    const int tid = threadIdx.x;

    #pragma unroll
    for (int t = 0; t < 4; ++t) colwin[tid + t*1024] = 0ull;
    __syncthreads();

    unsigned long long keys[4];
    #pragma unroll
    for (int t = 0; t < 4; ++t){
        const int i = tid + t*1024;
        unsigned long long key = rowmax[i];
        keys[t] = key;
        unsigned hi = (unsigned)(key >> 32);
        float v = sort2f(hi);
        if (v > 0.3f){
            int j = NDET - 1 - (int)(key & 0xffffffffu);
            unsigned long long ck =
                ((unsigned long long)hi << 32) | (unsigned)(NDET - 1 - i);
            atomicMax(&colwin[j], ck);
        }
    }
    __syncthreads();

    #pragma unroll
    for (int t = 0; t < 4; ++t){
        const int i = tid + t*1024;
        unsigned long long key = keys[t];
        unsigned hi = (unsigned)(key >> 32);
        float v = sort2f(hi);
        int j = NDET - 1 - (int)(key & 0xffffffffu);
        unsigned long long ck =
            ((unsigned long long)hi << 32) | (unsigned)(NDET - 1 - i);
        matches[i] = (v > 0.3f && colwin[j] == ck) ? (float)j : -1.0f;
    }
}

// ---------------------------------------------------------------------------
extern "C" void kernel_launch(void* const* d_in, const int* in_sizes, int n_in,
                              void* d_out, int out_size, void* d_ws, size_t ws_size,
                              hipStream_t stream)
{
    const float* det_t  = (const float*)d_in[0];
    const float* det_t1 = (const float*)d_in[1];
    const float* Wp1 = (const float*)d_in[2];
    const float* bp1 = (const float*)d_in[3];
    const float* Wp2 = (const float*)d_in[4];
    const float* bp2 = (const float*)d_in[5];
    const float* Wa1 = (const float*)d_in[6];
    const float* ba1 = (const float*)d_in[7];
    const float* Wa2 = (const float*)d_in[8];
    const float* ba2 = (const float*)d_in[9];

    float* out     = (float*)d_out;
    float* matches = out;            // 4096 elements (written as float)
    float* sim     = out + NDET;     // 4096*4096

    char* ws = (char*)d_ws;
    unsigned long long* rowmax = (unsigned long long*)ws;      // 32 KiB
    _Float16* Ahi = (_Float16*)(ws + 32768);                   // 4096*64 fp16 = 512 KiB
    _Float16* Alo = Ahi + (size_t)NDET * KPAD;                 // 512 KiB
    _Float16* Bhi = Alo + (size_t)NDET * KPAD;                 // 512 KiB
    _Float16* Blo = Bhi + (size_t)NDET * KPAD;                 // 512 KiB

    hipMemsetAsync(d_ws, 0, 32768, stream);  // zero rowmax only

    encode_kernel<<<1024, 256, 0, stream>>>(
        det_t, det_t1, Wp1, bp1, Wp2, bp2, Wa1, ba1, Wa2, ba2, Ahi, Alo, Bhi, Blo);

    sim_kernel<<<dim3(NDET / 128, NDET / 128), 256, 0, stream>>>(
        Ahi, Alo, Bhi, Blo, sim, rowmax);

    match_kernel<<<1, 1024, 0, stream>>>(rowmax, matches);
}